// Round 4
// baseline (388.082 us; speedup 1.0000x reference)
//
#include <hip/hip_runtime.h>
#include <hip/hip_bf16.h>
#include <math.h>

#define S 2048
#define D 64
#define H 16
#define BR 64              // Q rows per block
#define BC 64              // K cols per tile
#define NIT (S / BC)       // 32 K-tiles
#define KSTR 72            // 144 B rows: conflict-free b128 reads + b64 writes, 16B-aligned
#define VSTR 84            // 168 B rows: conflict-free b64 writes AND b64-pair reads

typedef __attribute__((ext_vector_type(8))) short bf16x8;
typedef __attribute__((ext_vector_type(4))) short bf16x4;
typedef __attribute__((ext_vector_type(4))) float f32x4;

// hardware packed f32->bf16 RTNE (v_cvt_pk_bf16_f32); bit-identical to manual RTNE
__device__ __forceinline__ unsigned pk2(float a, float b) {
    __hip_bfloat162 h2 = __float22bfloat162_rn(make_float2(a, b));
    unsigned u; __builtin_memcpy(&u, &h2, 4);
    return u;
}

#define LGKM0() asm volatile("s_waitcnt lgkmcnt(0)" ::: "memory")
#define BAR()   __builtin_amdgcn_s_barrier()

// Single-barrier-per-tile double-buffered fused attention.
// Swapped-operand MFMAs throughout (lane owns 4 consecutive fast-axis outputs).
__global__ __launch_bounds__(256, 2)
void k_attn_fused(const float* __restrict__ Q, const float* __restrict__ K,
                  const float* __restrict__ V, float* __restrict__ ctx,
                  float* __restrict__ attn) {
    __shared__ __align__(16) unsigned short Qs[BR * KSTR];      // 9216 B; Phi alias (pass B)
    __shared__ __align__(16) unsigned short Ks[2][BC * KSTR];   // 18432 B double-buffered
    __shared__ __align__(16) unsigned short Vthi[2][D * VSTR];  // 21504 B dbuf, Vt[d][k]
    __shared__ __align__(16) unsigned short Vtlo[2][D * VSTR];  // 21504 B dbuf
    __shared__ __align__(16) unsigned short Plo[BR * KSTR];     // 9216 B
    unsigned short* Phi = Qs;   // Qs is dead after bq register load
    // total 79872 B -> 2 blocks/CU (grid is 2/CU anyway)

    // XCD-clustered remap: each XCD (bid&7) owns 2 heads -> K/V set (2MB) fits its L2
    const int bid = blockIdx.x;
    const int idx_in = bid >> 3;
    const int h  = ((bid & 7) << 1) | (idx_in >> 5);
    const int r0 = (idx_in & 31) * BR;

    const int t  = threadIdx.x;
    const int w    = t >> 6;
    const int lane = t & 63;
    const int l16  = lane & 15;
    const int quad = lane >> 4;
    const int rb   = t >> 4;           // staging row base (16 threads/row)
    const int c4   = (t & 15) * 4;     // staging col (float4 granularity)

    const float* Qh = Q + (size_t)h * S * D;
    const float* Kh = K + (size_t)h * S * D;
    const float* Vh = V + (size_t)h * S * D;

    float4 kreg[4];
    float  vr[16];

    auto loadK = [&](int tile) {
#pragma unroll
        for (int p = 0; p < 4; ++p)
            kreg[p] = *(const float4*)(Kh + ((size_t)tile * BC + rb + p * 16) * D + c4);
    };
    auto loadV = [&](int tile) {
#pragma unroll
        for (int p = 0; p < 4; ++p)
#pragma unroll
            for (int i = 0; i < 4; ++i)   // coalesced: one V row per wave-instruction
                vr[p * 4 + i] = Vh[((size_t)tile * BC + w * 16 + p * 4 + i) * D + lane];
    };
    auto stageK = [&](int buf) {
#pragma unroll
        for (int p = 0; p < 4; ++p) {
            int r = rb + p * 16;
            *(uint2*)&Ks[buf][r * KSTR + c4] =
                make_uint2(pk2(kreg[p].x, kreg[p].y), pk2(kreg[p].z, kreg[p].w));
        }
    };
    auto stageV = [&](int buf) {      // thread owns d=lane, 16 consecutive k: reg transpose
#pragma unroll
        for (int p = 0; p < 4; ++p) {
            const int kb = w * 16 + p * 4;
            unsigned uh01 = pk2(vr[p * 4 + 0], vr[p * 4 + 1]);
            unsigned uh23 = pk2(vr[p * 4 + 2], vr[p * 4 + 3]);
            *(uint2*)&Vthi[buf][lane * VSTR + kb] = make_uint2(uh01, uh23);
            float l0 = vr[p * 4 + 0] - __uint_as_float(uh01 << 16);
            float l1 = vr[p * 4 + 1] - __uint_as_float(uh01 & 0xffff0000u);
            float l2 = vr[p * 4 + 2] - __uint_as_float(uh23 << 16);
            float l3 = vr[p * 4 + 3] - __uint_as_float(uh23 & 0xffff0000u);
            *(uint2*)&Vtlo[buf][lane * VSTR + kb] = make_uint2(pk2(l0, l1), pk2(l2, l3));
        }
    };

    // ---- stage Q tile (64x64 fp32 -> bf16 LDS), coalesced float4 ----
#pragma unroll
    for (int p = 0; p < 4; ++p) {
        int r = rb + p * 16;
        float4 v = *(const float4*)(Qh + (size_t)(r0 + r) * D + c4);
        *(uint2*)&Qs[r * KSTR + c4] = make_uint2(pk2(v.x, v.y), pk2(v.z, v.w));
    }
    LGKM0(); BAR();

    // persistent Q frags (B-operand in swapped mode): row q = w*16+l16
    bf16x8 bq[2];
    bq[0] = *(const bf16x8*)&Qs[(w * 16 + l16) * KSTR + 0 * 32 + quad * 8];
    bq[1] = *(const bf16x8*)&Qs[(w * 16 + l16) * KSTR + 1 * 32 + quad * 8];

    const f32x4 zero4 = {0.f, 0.f, 0.f, 0.f};
    float lsum = 0.f;

    // =================== Pass A: denominators (1 barrier/tile, K dbuf) ===============
    loadK(0);
    stageK(0);
    loadK(1);
    for (int kt = 0; kt < NIT; ++kt) {
        const int cur = kt & 1;
        LGKM0(); BAR();
        // S^T = mfma(K-frag, Q-frag): lane holds k = cs*16+quad*4+reg at q = w*16+l16
        f32x4 acc[4] = {zero4, zero4, zero4, zero4};
#pragma unroll
        for (int ks = 0; ks < 2; ++ks)
#pragma unroll
            for (int cs = 0; cs < 4; ++cs) {
                bf16x8 ak = *(const bf16x8*)&Ks[cur][(cs * 16 + l16) * KSTR + ks * 32 + quad * 8];
                acc[cs] = __builtin_amdgcn_mfma_f32_16x16x32_bf16(ak, bq[ks], acc[cs], 0, 0, 0);
            }
        if (kt + 1 < NIT) stageK(cur ^ 1);    // writes next buffer: no intra-region hazard
        if (kt + 2 < NIT) loadK(kt + 2);      // stays in flight across the barrier
        float e = 0.f;
#pragma unroll
        for (int cs = 0; cs < 4; ++cs)
#pragma unroll
            for (int r2 = 0; r2 < 4; ++r2)
                e += __expf(acc[cs][r2] * 0.125f);
        e += __shfl_xor(e, 16);               // reduce over the 4 quads of this q row
        e += __shfl_xor(e, 32);
        lsum += e;
    }
    const float linv = 1.0f / lsum;

    // =================== Pass B: attn write + P@V (1 barrier/tile, K+V dbuf) =========
    f32x4 cacc[4] = {zero4, zero4, zero4, zero4};
    loadK(0); loadV(0);
    stageK(0); stageV(0);
    loadK(1); loadV(1);
    for (int kt = 0; kt < NIT; ++kt) {
        const int cur = kt & 1;
        LGKM0(); BAR();
        // QK^T (swapped) from Ks[cur]
        f32x4 acc[4] = {zero4, zero4, zero4, zero4};
#pragma unroll
        for (int ks = 0; ks < 2; ++ks)
#pragma unroll
            for (int cs = 0; cs < 4; ++cs) {
                bf16x8 ak = *(const bf16x8*)&Ks[cur][(cs * 16 + l16) * KSTR + ks * 32 + quad * 8];
                acc[cs] = __builtin_amdgcn_mfma_f32_16x16x32_bf16(ak, bq[ks], acc[cs], 0, 0, 0);
            }
        if (kt + 1 < NIT) { stageK(cur ^ 1); stageV(cur ^ 1); }
        if (kt + 2 < NIT) { loadK(kt + 2); loadV(kt + 2); }

        // softmax: normalize, direct f32x4 nontemporal attn store, P hi/lo staging [q][k]
        const int prow = (w * 16 + l16) * KSTR;
        float* arow = attn + (size_t)(h * S + r0 + w * 16 + l16) * S + (size_t)kt * BC;
#pragma unroll
        for (int cs = 0; cs < 4; ++cs) {
            f32x4 pv;
#pragma unroll
            for (int r2 = 0; r2 < 4; ++r2)
                pv[r2] = __expf(acc[cs][r2] * 0.125f) * linv;
            __builtin_nontemporal_store(pv, (f32x4*)(arow + cs * 16 + quad * 4));
            unsigned uh01 = pk2(pv[0], pv[1]);
            unsigned uh23 = pk2(pv[2], pv[3]);
            *(uint2*)&Phi[prow + cs * 16 + quad * 4] = make_uint2(uh01, uh23);
            float l0 = pv[0] - __uint_as_float(uh01 << 16);
            float l1 = pv[1] - __uint_as_float(uh01 & 0xffff0000u);
            float l2 = pv[2] - __uint_as_float(uh23 << 16);
            float l3 = pv[3] - __uint_as_float(uh23 & 0xffff0000u);
            *(uint2*)&Plo[prow + cs * 16 + quad * 4] = make_uint2(pk2(l0, l1), pk2(l2, l3));
        }
        // P staging is intra-wave (rows w*16..w*16+15 written & read only by wave w):
        // program order + compiler lgkm waits order the ds_write -> ds_read chain.

        // P @ V (swapped): cacc[vs] over d = vs*16+quad*4+reg at q = w*16+l16
#pragma unroll
        for (int ks = 0; ks < 2; ++ks) {
            bf16x8 ah = *(const bf16x8*)&Phi[prow + ks * 32 + quad * 8];
            bf16x8 al = *(const bf16x8*)&Plo[prow + ks * 32 + quad * 8];
#pragma unroll
            for (int vs = 0; vs < 4; ++vs) {
                const int vo = (vs * 16 + l16) * VSTR + ks * 32 + quad * 8;
                // 168B rows are 8B-aligned: explicit b64-pair loads (conflict-free)
                bf16x4 h0 = *(const bf16x4*)&Vthi[cur][vo];
                bf16x4 h1 = *(const bf16x4*)&Vthi[cur][vo + 4];
                bf16x4 g0 = *(const bf16x4*)&Vtlo[cur][vo];
                bf16x4 g1 = *(const bf16x4*)&Vtlo[cur][vo + 4];
                bf16x8 bh = __builtin_shufflevector(h0, h1, 0, 1, 2, 3, 4, 5, 6, 7);
                bf16x8 bl = __builtin_shufflevector(g0, g1, 0, 1, 2, 3, 4, 5, 6, 7);
                cacc[vs] = __builtin_amdgcn_mfma_f32_16x16x32_bf16(bh, ah, cacc[vs], 0, 0, 0);
                cacc[vs] = __builtin_amdgcn_mfma_f32_16x16x32_bf16(bl, ah, cacc[vs], 0, 0, 0);
                cacc[vs] = __builtin_amdgcn_mfma_f32_16x16x32_bf16(bh, al, cacc[vs], 0, 0, 0);
            }
        }
    }

    // epilogue: ctx store, f32x4 per lane (lane owns q row, 4 consecutive d)
    float* crow = ctx + (size_t)(h * S + r0 + w * 16 + l16) * D;
#pragma unroll
    for (int vs = 0; vs < 4; ++vs)
        *(f32x4*)(crow + vs * 16 + quad * 4) = cacc[vs];
}

extern "C" void kernel_launch(void* const* d_in, const int* in_sizes, int n_in,
                              void* d_out, int out_size, void* d_ws, size_t ws_size,
                              hipStream_t stream) {
    (void)in_sizes; (void)n_in; (void)d_ws; (void)ws_size; (void)out_size;
    const float* Q = (const float*)d_in[0];
    const float* K = (const float*)d_in[1];
    const float* V = (const float*)d_in[2];
    float* ctx  = (float*)d_out;                          // [16,2048,64]
    float* attn = (float*)d_out + (size_t)H * S * D;      // [16,2048,2048]

    k_attn_fused<<<dim3((S / BR) * H), 256, 0, stream>>>(Q, K, V, ctx, attn);
}